// Round 3
// baseline (349.113 us; speedup 1.0000x reference)
//
#include <hip/hip_runtime.h>
#include <hip/hip_bf16.h>

#define LSEQ 20000
#define DEG  16
#define F    128
#define ALPHA 0.2f
#define GRID 1024   // 256 CU x 4 blocks/CU, exact co-residency (32KB LDS, VGPR<=128)

typedef __bf16 bf16x8 __attribute__((ext_vector_type(8)));
typedef float  f32x4  __attribute__((ext_vector_type(4)));

__device__ __forceinline__ float bf_lo(unsigned int u) { return __uint_as_float(u << 16); }
__device__ __forceinline__ float bf_hi(unsigned int u) { return __uint_as_float(u & 0xffff0000u); }
__device__ __forceinline__ float elu_f(float v) { return v > 0.f ? v : __expf(v) - 1.f; }

// Prep: wt[n*F+k] = bf16(W[k*F+n]) (32 KB), wa[k] = (W@a1)[k], wa[F+k] =
// (W@a2)[k], and bar = 0 (workspace is re-poisoned between runs, so the
// barrier counter must be zeroed every launch). Kernel-boundary release/
// acquire makes all of it visible to gat_fused (same mechanism the passing
// 3-kernel version used for wt).
__global__ __launch_bounds__(256) void gat_prep(const float* __restrict__ W,
                                                const float* __restrict__ a,
                                                __hip_bfloat16* __restrict__ wt,
                                                float* __restrict__ wa,
                                                unsigned int* __restrict__ bar)
{
    const int t = blockIdx.x * 256 + threadIdx.x;
    for (int i = t; i < F * F; i += 16 * 256) {
        const int k = i >> 7, n = i & (F - 1);
        wt[n * F + k] = __float2bfloat16(W[i]);
    }
    if (blockIdx.x == 0 && threadIdx.x < F) {
        const int k = threadIdx.x;
        float acc1 = 0.f, acc2 = 0.f;
        for (int n = 0; n < F; ++n) {
            const float w = W[k * F + n];
            acc1 = fmaf(w, a[n],     acc1);
            acc2 = fmaf(w, a[F + n], acc2);
        }
        wa[k]     = acc1;
        wa[F + k] = acc2;
    }
    if (blockIdx.x == 15 && threadIdx.x == 0) *bar = 0u;
}

// R11: fused gemm+attn in ONE plain-launched kernel. R10's cooperative
// launch silently failed (output stayed zero -> absmax 6.25 = max|ref|);
// replaced grid.sync with a monotonic-counter device barrier:
//   arrive: __threadfence (L2 writeback, release) + atomicAdd(bar,1)
//   wait:   spin on atomicAdd(bar,0) >= GRID (device-scope, cross-XCD ok)
//   depart: __threadfence (L2 invalidate, acquire)
// Co-residency is exact by construction: launch_bounds(256,4) caps VGPR at
// 128 -> 4 blocks/CU; grid = 256*4 = 1024. Phase B/C bodies are
// bit-identical to the R9 split kernels -> absmax 0.03125.
__global__ __launch_bounds__(256, 4) void gat_fused(
    const float* __restrict__ x,
    const int*   __restrict__ adj,
    const __hip_bfloat16* __restrict__ wt,
    const float* __restrict__ wa,
    __hip_bfloat16* __restrict__ y16,
    float* __restrict__ s1,
    float* __restrict__ s2,
    float* __restrict__ out,
    unsigned int* __restrict__ bar,
    int BL)
{
    __shared__ __hip_bfloat16 wl[F][F];   // 32 KB exactly

    const int bid  = blockIdx.x;
    const int t    = threadIdx.x;
    const int lane = t & 63;
    const int wid  = t >> 6;

    // ---------------- Phase B: gemm. Stage wt -> LDS once (XOR-swizzled
    // 16B chunks: phys chunk = c8 ^ (row&7); row&7 == m&7 hoists the XOR
    // out of the ct loop; bank groups stay balanced).
    {
        const uint4* wg = reinterpret_cast<const uint4*>(wt);
        #pragma unroll
        for (int i = 0; i < 8; ++i) {
            const int g   = t + 256 * i;       // global uint4 index
            const int row = g >> 4;            // 16 uint4 per row
            const int c8  = g & 15;            // logical 8-half chunk
            *reinterpret_cast<uint4*>(&wl[row][((c8 ^ (row & 7)) * 8)]) = wg[g];
        }
    }
    __syncthreads();   // wl ready; read-only below

    const int m = lane & 15;
    const int q = lane >> 4;
    const int NU = BL / 64;            // 1250 row-units

    for (int u = bid; u < NU; u += GRID) {
        const int i0 = u * 64 + wid * 16;   // 16 x-rows per wave

        // fp32 x chunks: lane holds x[i0+m][q*8 + kt*32 + j], j=0..7.
        const float* xr = x + (size_t)(i0 + m) * F + q * 8;
        float4 xf[8];
        #pragma unroll
        for (int kt = 0; kt < 4; ++kt) {
            xf[2*kt]   = *reinterpret_cast<const float4*>(xr + kt * 32);
            xf[2*kt+1] = *reinterpret_cast<const float4*>(xr + kt * 32 + 4);
        }

        // s1/s2: fp32 dot with wa1/wa2 over this lane's 32 k's, reduce over q.
        float p1 = 0.f, p2 = 0.f;
        {
            const float* w1p = wa + q * 8;
            const float* w2p = wa + F + q * 8;
            #pragma unroll
            for (int kt = 0; kt < 4; ++kt) {
                const float4 u0 = *reinterpret_cast<const float4*>(w1p + kt * 32);
                const float4 u1 = *reinterpret_cast<const float4*>(w1p + kt * 32 + 4);
                const float4 v0 = *reinterpret_cast<const float4*>(w2p + kt * 32);
                const float4 v1 = *reinterpret_cast<const float4*>(w2p + kt * 32 + 4);
                const float4 xa = xf[2*kt], xb = xf[2*kt+1];
                p1 = fmaf(xa.x,u0.x,p1); p1 = fmaf(xa.y,u0.y,p1);
                p1 = fmaf(xa.z,u0.z,p1); p1 = fmaf(xa.w,u0.w,p1);
                p1 = fmaf(xb.x,u1.x,p1); p1 = fmaf(xb.y,u1.y,p1);
                p1 = fmaf(xb.z,u1.z,p1); p1 = fmaf(xb.w,u1.w,p1);
                p2 = fmaf(xa.x,v0.x,p2); p2 = fmaf(xa.y,v0.y,p2);
                p2 = fmaf(xa.z,v0.z,p2); p2 = fmaf(xa.w,v0.w,p2);
                p2 = fmaf(xb.x,v1.x,p2); p2 = fmaf(xb.y,v1.y,p2);
                p2 = fmaf(xb.z,v1.z,p2); p2 = fmaf(xb.w,v1.w,p2);
            }
        }
        p1 += __shfl_xor(p1, 16); p1 += __shfl_xor(p1, 32);
        p2 += __shfl_xor(p2, 16); p2 += __shfl_xor(p2, 32);
        if (lane < 16) {
            s1[i0 + m] = p1;
            s2[i0 + m] = p2;
        }

        // B-fragments (x^T): B[k=q*8+j][n=m] = x[i0+m][k].
        bf16x8 bfr[4];
        #pragma unroll
        for (int kt = 0; kt < 4; ++kt) {
            const float4 qa = xf[2*kt], qb = xf[2*kt+1];
            bf16x8 f;
            f[0] = (__bf16)qa.x; f[1] = (__bf16)qa.y; f[2] = (__bf16)qa.z; f[3] = (__bf16)qa.w;
            f[4] = (__bf16)qb.x; f[5] = (__bf16)qb.y; f[6] = (__bf16)qb.z; f[7] = (__bf16)qb.w;
            bfr[kt] = f;
        }

        // ct loop over 8 column tiles; A-frag from LDS: A[mm=m][k=q*8+j].
        #pragma unroll
        for (int ct = 0; ct < 8; ++ct) {
            union { uint4 u; bf16x8 v; } afr[4];
            const int row = ct * 16 + m;
            #pragma unroll
            for (int kt = 0; kt < 4; ++kt)
                afr[kt].u = *reinterpret_cast<const uint4*>(
                                &wl[row][(((kt * 4 + q) ^ (m & 7)) * 8)]);

            f32x4 acc = {0.f, 0.f, 0.f, 0.f};
            #pragma unroll
            for (int kt = 0; kt < 4; ++kt)
                acc = __builtin_amdgcn_mfma_f32_16x16x32_bf16(afr[kt].v, bfr[kt], acc, 0, 0, 0);

            union { uint2 u; __hip_bfloat162 h[2]; } pk;
            pk.h[0] = __float22bfloat162_rn(make_float2(acc[0], acc[1]));
            pk.h[1] = __float22bfloat162_rn(make_float2(acc[2], acc[3]));
            *reinterpret_cast<uint2*>(y16 + (size_t)(i0 + m) * F + ct * 16 + q * 4) = pk.u;
        }
    }

    // ---------------- Device-wide barrier (monotonic counter, no reset).
    __syncthreads();                       // all waves' stores drained (vmcnt0 before s_barrier)
    if (t == 0) {
        __threadfence();                   // release: L2 writeback
        atomicAdd(bar, 1u);
        while (atomicAdd(bar, 0u) < (unsigned)GRID)
            __builtin_amdgcn_s_sleep(2);
        __threadfence();                   // acquire: L2 invalidate
    }
    __syncthreads();

    // ---------------- Phase C: attn. Lane (g=lane>>4, d=lane&15) owns
    // output features [d*8, d*8+8) of node g0+g. v&7 == bid&7 keeps the
    // XCD-pair <-> batch pinning (GRID % 8 == 0).
    {
        const int d   = lane & 15;
        const int g16 = lane & 48;
        const int NV  = BL / 16;       // 5000 16-node groups

        for (int v = bid; v < NV; v += GRID) {
            const int x8    = v & 7;
            const int j     = v >> 3;                  // 0..624
            const int batch = x8 >> 1;                 // XCD pair -> batch
            const int grp   = j * 2 + (x8 & 1);        // 0..1249
            const int base  = batch * LSEQ;
            const int g0    = base + grp * 16 + wid * 4;

            // adj for 4 nodes: 64 contiguous ints, fully coalesced.
            const int av = adj[(size_t)g0 * DEG + lane];

            const float sv = s1[base + av];
            float s2l = (d == 0) ? s2[base + av] : 0.f;
            const float s2v = __shfl(s2l, g16);
            const float e = sv + s2v;
            const float tv = e > 0.f ? e : ALPHA * e;

            // softmax within each 16-lane group.
            float mx = tv;
            #pragma unroll
            for (int off = 1; off < 16; off <<= 1) mx = fmaxf(mx, __shfl_xor(mx, off));
            const float w = __expf(tv - mx);
            float p = w;
            #pragma unroll
            for (int off = 1; off < 16; off <<= 1) p += __shfl_xor(p, off);
            const float attn = w / p;

            // Gather: 16B per lane per neighbor row; 4 rows per instruction.
            const char* yb = reinterpret_cast<const char*>(y16 + ((size_t)base << 7)) + d * 16;
            float acc[8] = {0.f, 0.f, 0.f, 0.f, 0.f, 0.f, 0.f, 0.f};

            uint4 va[8], vb[8];
            #pragma unroll
            for (int k = 0; k < 8; ++k) {
                const int r = __shfl(av, g16 + k);
                va[k] = *reinterpret_cast<const uint4*>(yb + ((size_t)r << 8));
            }
            #pragma unroll
            for (int k = 0; k < 8; ++k) {
                const int r = __shfl(av, g16 + 8 + k);
                vb[k] = *reinterpret_cast<const uint4*>(yb + ((size_t)r << 8));
            }

            #pragma unroll
            for (int k = 0; k < 8; ++k) {
                const float wk = __shfl(attn, g16 + k);
                const uint4 vv = va[k];
                acc[0] = fmaf(wk, bf_lo(vv.x), acc[0]);
                acc[1] = fmaf(wk, bf_hi(vv.x), acc[1]);
                acc[2] = fmaf(wk, bf_lo(vv.y), acc[2]);
                acc[3] = fmaf(wk, bf_hi(vv.y), acc[3]);
                acc[4] = fmaf(wk, bf_lo(vv.z), acc[4]);
                acc[5] = fmaf(wk, bf_hi(vv.z), acc[5]);
                acc[6] = fmaf(wk, bf_lo(vv.w), acc[6]);
                acc[7] = fmaf(wk, bf_hi(vv.w), acc[7]);
            }
            #pragma unroll
            for (int k = 0; k < 8; ++k) {
                const float wk = __shfl(attn, g16 + 8 + k);
                const uint4 vv = vb[k];
                acc[0] = fmaf(wk, bf_lo(vv.x), acc[0]);
                acc[1] = fmaf(wk, bf_hi(vv.x), acc[1]);
                acc[2] = fmaf(wk, bf_lo(vv.y), acc[2]);
                acc[3] = fmaf(wk, bf_hi(vv.y), acc[3]);
                acc[4] = fmaf(wk, bf_lo(vv.z), acc[4]);
                acc[5] = fmaf(wk, bf_hi(vv.z), acc[5]);
                acc[6] = fmaf(wk, bf_lo(vv.w), acc[6]);
                acc[7] = fmaf(wk, bf_hi(vv.w), acc[7]);
            }

            // ELU + store: node g0+g, features [d*8, d*8+8).
            float* op = out + (size_t)(g0 + (lane >> 4)) * F + d * 8;
            const float4 o0 = make_float4(elu_f(acc[0]), elu_f(acc[1]),
                                          elu_f(acc[2]), elu_f(acc[3]));
            const float4 o1 = make_float4(elu_f(acc[4]), elu_f(acc[5]),
                                          elu_f(acc[6]), elu_f(acc[7]));
            *reinterpret_cast<float4*>(op)     = o0;
            *reinterpret_cast<float4*>(op + 4) = o1;
        }
    }
}

extern "C" void kernel_launch(void* const* d_in, const int* in_sizes, int n_in,
                              void* d_out, int out_size, void* d_ws, size_t ws_size,
                              hipStream_t stream) {
    const float* x   = (const float*)d_in[0];
    const int*   adj = (const int*)d_in[1];
    const float* W   = (const float*)d_in[2];
    const float* a   = (const float*)d_in[3];
    float* out = (float*)d_out;

    const int BL = in_sizes[0] / F;   // bs*L = 80000

    __hip_bfloat16* y16 = (__hip_bfloat16*)d_ws;
    float* s1 = (float*)((char*)d_ws + (size_t)BL * F * sizeof(__hip_bfloat16));
    float* s2 = s1 + BL;
    __hip_bfloat16* wt = (__hip_bfloat16*)(s2 + BL);
    float* wa = (float*)(wt + F * F);
    unsigned int* bar = (unsigned int*)(wa + 2 * F);

    gat_prep <<<16,   256, 0, stream>>>(W, a, wt, wa, bar);
    gat_fused<<<GRID, 256, 0, stream>>>(x, adj, wt, wa, y16, s1, s2, out, bar, BL);
}

// Round 4
// 190.968 us; speedup vs baseline: 1.8281x; 1.8281x over previous
//
#include <hip/hip_runtime.h>
#include <hip/hip_bf16.h>

#define LSEQ 20000
#define DEG  16
#define F    128
#define ALPHA 0.2f
#define GRID 1024   // 256 CU x 4 blocks/CU, exact co-residency (32KB LDS, VGPR<=128)
#define UB   313    // 64-row units per batch (ceil(20000/64)); last unit is half
#define BPP  256    // blocks per XCD pair (GRID/4)

typedef __bf16 bf16x8 __attribute__((ext_vector_type(8)));
typedef float  f32x4  __attribute__((ext_vector_type(4)));

__device__ __forceinline__ float bf_lo(unsigned int u) { return __uint_as_float(u << 16); }
__device__ __forceinline__ float bf_hi(unsigned int u) { return __uint_as_float(u & 0xffff0000u); }
__device__ __forceinline__ float elu_f(float v) { return v > 0.f ? v : __expf(v) - 1.f; }

// Prep: wt[n*F+k] = bf16(W[k*F+n]) (32 KB), wa[k] = (W@a1)[k], wa[F+k] =
// (W@a2)[k], and zero the 4 per-pair barrier counters (workspace is
// re-poisoned between runs). Kernel-boundary release/acquire makes all of
// it visible to gat_fused.
__global__ __launch_bounds__(256) void gat_prep(const float* __restrict__ W,
                                                const float* __restrict__ a,
                                                __hip_bfloat16* __restrict__ wt,
                                                float* __restrict__ wa,
                                                unsigned int* __restrict__ bar)
{
    const int t = blockIdx.x * 256 + threadIdx.x;
    for (int i = t; i < F * F; i += 16 * 256) {
        const int k = i >> 7, n = i & (F - 1);
        wt[n * F + k] = __float2bfloat16(W[i]);
    }
    if (blockIdx.x == 0 && threadIdx.x < F) {
        const int k = threadIdx.x;
        float acc1 = 0.f, acc2 = 0.f;
        for (int n = 0; n < F; ++n) {
            const float w = W[k * F + n];
            acc1 = fmaf(w, a[n],     acc1);
            acc2 = fmaf(w, a[F + n], acc2);
        }
        wa[k]     = acc1;
        wa[F + k] = acc2;
    }
    if (blockIdx.x == 15 && threadIdx.x < 128) bar[threadIdx.x] = 0u;
}

// R12: fused kernel, sane barrier. R11's 260us was a congestion collapse:
// ~1.7M same-line atomicAdd(bar,0) spin RMWs (the ~120MB symmetric excess
// in FETCH+WRITE) + per-block __threadfence wbl2+INV storms. Fixes:
//  (1) XCD-pair ownership: pair p = (bid&7)>>1 computes batch p's
//      y16/s1/s2 rows in phase B and consumes exactly those in phase C.
//  (2) Per-pair barrier (256 arrivals, own cacheline): release-only agent
//      fence (buffer_wbl2, NO invalidate -> gather L2 locality survives;
//      correct because no reader XCD can hold a stale line: phase B never
//      reads y16/s1/s2 and kernel-start invalidated L2), one relaxed
//      agent fetch_add arrival, spin on relaxed agent atomic LOAD +
//      s_sleep(16) (reads pipeline; no RMW storm).
// Per-row arithmetic identical to R9/R11 -> absmax 0.03125.
__global__ __launch_bounds__(256, 4) void gat_fused(
    const float* __restrict__ x,
    const int*   __restrict__ adj,
    const __hip_bfloat16* __restrict__ wt,
    const float* __restrict__ wa,
    __hip_bfloat16* __restrict__ y16,
    float* __restrict__ s1,
    float* __restrict__ s2,
    float* __restrict__ out,
    unsigned int* __restrict__ bar)
{
    __shared__ __hip_bfloat16 wl[F][F];   // 32 KB exactly

    const int bid  = blockIdx.x;
    const int t    = threadIdx.x;
    const int lane = t & 63;
    const int wid  = t >> 6;
    const int pair = (bid & 7) >> 1;                    // XCD pair == batch
    const int pidx = ((bid >> 3) << 1) | (bid & 1);     // 0..255 within pair

    // ---------------- Stage wt -> LDS (XOR-swizzled 16B chunks: phys chunk
    // = c8 ^ (row&7); row&7 == m&7 hoists the XOR out of the ct loop).
    {
        const uint4* wg = reinterpret_cast<const uint4*>(wt);
        #pragma unroll
        for (int i = 0; i < 8; ++i) {
            const int g   = t + 256 * i;       // global uint4 index
            const int row = g >> 4;            // 16 uint4 per row
            const int c8  = g & 15;            // logical 8-half chunk
            *reinterpret_cast<uint4*>(&wl[row][((c8 ^ (row & 7)) * 8)]) = wg[g];
        }
    }
    __syncthreads();   // wl ready; read-only below

    const int m = lane & 15;
    const int q = lane >> 4;

    // ---------------- Phase B: gemm over this pair's batch only.
    for (int ub = pidx; ub < UB; ub += BPP) {
        const int local = ub * 64 + wid * 16;
        if (local < LSEQ) {
            const size_t r0 = (size_t)pair * LSEQ + local;   // wave's 16 rows

            // fp32 x chunks: lane holds x[r0+m][q*8 + kt*32 + j], j=0..7.
            const float* xr = x + (r0 + m) * F + q * 8;
            float4 xf[8];
            #pragma unroll
            for (int kt = 0; kt < 4; ++kt) {
                xf[2*kt]   = *reinterpret_cast<const float4*>(xr + kt * 32);
                xf[2*kt+1] = *reinterpret_cast<const float4*>(xr + kt * 32 + 4);
            }

            // s1/s2: fp32 dot with wa1/wa2 over this lane's 32 k's, reduce over q.
            float p1 = 0.f, p2 = 0.f;
            {
                const float* w1p = wa + q * 8;
                const float* w2p = wa + F + q * 8;
                #pragma unroll
                for (int kt = 0; kt < 4; ++kt) {
                    const float4 u0 = *reinterpret_cast<const float4*>(w1p + kt * 32);
                    const float4 u1 = *reinterpret_cast<const float4*>(w1p + kt * 32 + 4);
                    const float4 v0 = *reinterpret_cast<const float4*>(w2p + kt * 32);
                    const float4 v1 = *reinterpret_cast<const float4*>(w2p + kt * 32 + 4);
                    const float4 xa = xf[2*kt], xb = xf[2*kt+1];
                    p1 = fmaf(xa.x,u0.x,p1); p1 = fmaf(xa.y,u0.y,p1);
                    p1 = fmaf(xa.z,u0.z,p1); p1 = fmaf(xa.w,u0.w,p1);
                    p1 = fmaf(xb.x,u1.x,p1); p1 = fmaf(xb.y,u1.y,p1);
                    p1 = fmaf(xb.z,u1.z,p1); p1 = fmaf(xb.w,u1.w,p1);
                    p2 = fmaf(xa.x,v0.x,p2); p2 = fmaf(xa.y,v0.y,p2);
                    p2 = fmaf(xa.z,v0.z,p2); p2 = fmaf(xa.w,v0.w,p2);
                    p2 = fmaf(xb.x,v1.x,p2); p2 = fmaf(xb.y,v1.y,p2);
                    p2 = fmaf(xb.z,v1.z,p2); p2 = fmaf(xb.w,v1.w,p2);
                }
            }
            p1 += __shfl_xor(p1, 16); p1 += __shfl_xor(p1, 32);
            p2 += __shfl_xor(p2, 16); p2 += __shfl_xor(p2, 32);
            if (lane < 16) {
                s1[r0 + m] = p1;
                s2[r0 + m] = p2;
            }

            // B-fragments (x^T): B[k=q*8+j][n=m] = x[r0+m][k].
            bf16x8 bfr[4];
            #pragma unroll
            for (int kt = 0; kt < 4; ++kt) {
                const float4 qa = xf[2*kt], qb = xf[2*kt+1];
                bf16x8 f;
                f[0] = (__bf16)qa.x; f[1] = (__bf16)qa.y; f[2] = (__bf16)qa.z; f[3] = (__bf16)qa.w;
                f[4] = (__bf16)qb.x; f[5] = (__bf16)qb.y; f[6] = (__bf16)qb.z; f[7] = (__bf16)qb.w;
                bfr[kt] = f;
            }

            // ct loop over 8 column tiles; A-frag from LDS: A[mm=m][k=q*8+j].
            #pragma unroll
            for (int ct = 0; ct < 8; ++ct) {
                union { uint4 u; bf16x8 v; } afr[4];
                const int row = ct * 16 + m;
                #pragma unroll
                for (int kt = 0; kt < 4; ++kt)
                    afr[kt].u = *reinterpret_cast<const uint4*>(
                                    &wl[row][(((kt * 4 + q) ^ (m & 7)) * 8)]);

                f32x4 acc = {0.f, 0.f, 0.f, 0.f};
                #pragma unroll
                for (int kt = 0; kt < 4; ++kt)
                    acc = __builtin_amdgcn_mfma_f32_16x16x32_bf16(afr[kt].v, bfr[kt], acc, 0, 0, 0);

                union { uint2 u; __hip_bfloat162 h[2]; } pk;
                pk.h[0] = __float22bfloat162_rn(make_float2(acc[0], acc[1]));
                pk.h[1] = __float22bfloat162_rn(make_float2(acc[2], acc[3]));
                *reinterpret_cast<uint2*>(y16 + (r0 + m) * F + ct * 16 + q * 4) = pk.u;
            }
        }
    }

    // ---------------- Per-pair barrier (monotonic counter, release-only).
    __syncthreads();                       // all 4 waves' stores at L2 (vmcnt0 before s_barrier)
    {
        unsigned int* cnt = bar + pair * 32;   // own 128B line per pair
        if (t == 0) {
            __builtin_amdgcn_fence(__ATOMIC_RELEASE, "agent");   // buffer_wbl2, no inv
            __hip_atomic_fetch_add(cnt, 1u, __ATOMIC_RELAXED, __HIP_MEMORY_SCOPE_AGENT);
            while (__hip_atomic_load(cnt, __ATOMIC_RELAXED, __HIP_MEMORY_SCOPE_AGENT) < (unsigned)BPP)
                __builtin_amdgcn_s_sleep(16);
        }
        __syncthreads();
    }

    // ---------------- Phase C: attn over this pair's batch. Lane
    // (g=lane>>4, d=lane&15) owns output features [d*8, d*8+8) of node
    // g0+g. Same-XCD gather rows hit warm L2 (no invalidate happened).
    {
        const int d    = lane & 15;
        const int g16  = lane & 48;
        const int base = pair * LSEQ;

        for (int g = pidx; g < LSEQ / 16; g += BPP) {
            const int g0 = base + g * 16 + wid * 4;

            // adj for 4 nodes: 64 contiguous ints, fully coalesced.
            const int av = adj[(size_t)g0 * DEG + lane];

            const float sv = s1[base + av];
            float s2l = (d == 0) ? s2[base + av] : 0.f;
            const float s2v = __shfl(s2l, g16);
            const float e = sv + s2v;
            const float tv = e > 0.f ? e : ALPHA * e;

            // softmax within each 16-lane group.
            float mx = tv;
            #pragma unroll
            for (int off = 1; off < 16; off <<= 1) mx = fmaxf(mx, __shfl_xor(mx, off));
            const float w = __expf(tv - mx);
            float p = w;
            #pragma unroll
            for (int off = 1; off < 16; off <<= 1) p += __shfl_xor(p, off);
            const float attn = w / p;

            // Gather: 16B per lane per neighbor row; 4 rows per instruction.
            const char* yb = reinterpret_cast<const char*>(y16 + ((size_t)base << 7)) + d * 16;
            float acc[8] = {0.f, 0.f, 0.f, 0.f, 0.f, 0.f, 0.f, 0.f};

            uint4 va[8], vb[8];
            #pragma unroll
            for (int k = 0; k < 8; ++k) {
                const int r = __shfl(av, g16 + k);
                va[k] = *reinterpret_cast<const uint4*>(yb + ((size_t)r << 8));
            }
            #pragma unroll
            for (int k = 0; k < 8; ++k) {
                const int r = __shfl(av, g16 + 8 + k);
                vb[k] = *reinterpret_cast<const uint4*>(yb + ((size_t)r << 8));
            }

            #pragma unroll
            for (int k = 0; k < 8; ++k) {
                const float wk = __shfl(attn, g16 + k);
                const uint4 vv = va[k];
                acc[0] = fmaf(wk, bf_lo(vv.x), acc[0]);
                acc[1] = fmaf(wk, bf_hi(vv.x), acc[1]);
                acc[2] = fmaf(wk, bf_lo(vv.y), acc[2]);
                acc[3] = fmaf(wk, bf_hi(vv.y), acc[3]);
                acc[4] = fmaf(wk, bf_lo(vv.z), acc[4]);
                acc[5] = fmaf(wk, bf_hi(vv.z), acc[5]);
                acc[6] = fmaf(wk, bf_lo(vv.w), acc[6]);
                acc[7] = fmaf(wk, bf_hi(vv.w), acc[7]);
            }
            #pragma unroll
            for (int k = 0; k < 8; ++k) {
                const float wk = __shfl(attn, g16 + 8 + k);
                const uint4 vv = vb[k];
                acc[0] = fmaf(wk, bf_lo(vv.x), acc[0]);
                acc[1] = fmaf(wk, bf_hi(vv.x), acc[1]);
                acc[2] = fmaf(wk, bf_lo(vv.y), acc[2]);
                acc[3] = fmaf(wk, bf_hi(vv.y), acc[3]);
                acc[4] = fmaf(wk, bf_lo(vv.z), acc[4]);
                acc[5] = fmaf(wk, bf_hi(vv.z), acc[5]);
                acc[6] = fmaf(wk, bf_lo(vv.w), acc[6]);
                acc[7] = fmaf(wk, bf_hi(vv.w), acc[7]);
            }

            // ELU + store: node g0+g, features [d*8, d*8+8).
            float* op = out + (size_t)(g0 + (lane >> 4)) * F + d * 8;
            const float4 o0 = make_float4(elu_f(acc[0]), elu_f(acc[1]),
                                          elu_f(acc[2]), elu_f(acc[3]));
            const float4 o1 = make_float4(elu_f(acc[4]), elu_f(acc[5]),
                                          elu_f(acc[6]), elu_f(acc[7]));
            *reinterpret_cast<float4*>(op)     = o0;
            *reinterpret_cast<float4*>(op + 4) = o1;
        }
    }
}

extern "C" void kernel_launch(void* const* d_in, const int* in_sizes, int n_in,
                              void* d_out, int out_size, void* d_ws, size_t ws_size,
                              hipStream_t stream) {
    const float* x   = (const float*)d_in[0];
    const int*   adj = (const int*)d_in[1];
    const float* W   = (const float*)d_in[2];
    const float* a   = (const float*)d_in[3];
    float* out = (float*)d_out;

    const int BL = in_sizes[0] / F;   // bs*L = 80000

    __hip_bfloat16* y16 = (__hip_bfloat16*)d_ws;
    float* s1 = (float*)((char*)d_ws + (size_t)BL * F * sizeof(__hip_bfloat16));
    float* s2 = s1 + BL;
    __hip_bfloat16* wt = (__hip_bfloat16*)(s2 + BL);
    float* wa = (float*)(wt + F * F);
    unsigned int* bar = (unsigned int*)(wa + 2 * F);

    gat_prep <<<16,   256, 0, stream>>>(W, a, wt, wa, bar);
    gat_fused<<<GRID, 256, 0, stream>>>(x, adj, wt, wa, y16, s1, s2, out, bar);
}

// Round 6
// 145.643 us; speedup vs baseline: 2.3970x; 1.3112x over previous
//
#include <hip/hip_runtime.h>
#include <hip/hip_bf16.h>

#define LSEQ 20000
#define DEG  16
#define F    128
#define ALPHA 0.2f

typedef __bf16 bf16x8 __attribute__((ext_vector_type(8)));
typedef float  f32x4  __attribute__((ext_vector_type(4)));

__device__ __forceinline__ float bf_lo(unsigned int u) { return __uint_as_float(u << 16); }
__device__ __forceinline__ float bf_hi(unsigned int u) { return __uint_as_float(u & 0xffff0000u); }
__device__ __forceinline__ float elu_f(float v) { return v > 0.f ? v : __expf(v) - 1.f; }

// R14: barrier-free algebraic restructuring. out = elu((sum_d attn_d *
// x[nbr_d]) @ W) by linearity, and s1 = x@(W a1), s2 = x@(W a2). So the
// GEMM moves AFTER the gather (on z = attn-weighted x rows), y16 dies,
// and no device-wide barrier is needed anywhere. 3 independent kernels.

// Prep: wt[n*F+k] = bf16(W[k*F+n]) (32 KB), wa[k] = (W@a1)[k],
// wa[F+k] = (W@a2)[k].
__global__ __launch_bounds__(256) void gat_prep(const float* __restrict__ W,
                                                const float* __restrict__ a,
                                                __hip_bfloat16* __restrict__ wt,
                                                float* __restrict__ wa)
{
    const int t = blockIdx.x * 256 + threadIdx.x;
    for (int i = t; i < F * F; i += 16 * 256) {
        const int k = i >> 7, n = i & (F - 1);
        wt[n * F + k] = __float2bfloat16(W[i]);
    }
    if (blockIdx.x == 0 && threadIdx.x < F) {
        const int k = threadIdx.x;
        float acc1 = 0.f, acc2 = 0.f;
        for (int n = 0; n < F; ++n) {
            const float w = W[k * F + n];
            acc1 = fmaf(w, a[n],     acc1);
            acc2 = fmaf(w, a[F + n], acc2);
        }
        wa[k]     = acc1;
        wa[F + k] = acc2;
    }
}

// Rows pass: fp32 s1/s2 (bit-identical to the old phase-B path -> attn
// weights unchanged) + x16 = bf16(x) using the EXACT per-element casts the
// old GEMM B-fragment used. 64 rows per block, grid 1250, zero tail.
__global__ __launch_bounds__(256) void gat_rows(const float* __restrict__ x,
                                                const float* __restrict__ wa,
                                                __hip_bfloat16* __restrict__ x16,
                                                float* __restrict__ s1,
                                                float* __restrict__ s2)
{
    const int t    = threadIdx.x;
    const int lane = t & 63;
    const int wid  = t >> 6;
    const int m    = lane & 15;
    const int q    = lane >> 4;
    const size_t r0 = (size_t)blockIdx.x * 64 + wid * 16;

    // fp32 x chunks: lane holds x[r0+m][q*8 + kt*32 + j], j=0..7.
    const float* xr = x + (r0 + m) * F + q * 8;
    float4 xf[8];
    #pragma unroll
    for (int kt = 0; kt < 4; ++kt) {
        xf[2*kt]   = *reinterpret_cast<const float4*>(xr + kt * 32);
        xf[2*kt+1] = *reinterpret_cast<const float4*>(xr + kt * 32 + 4);
    }

    // s1/s2: fp32 dot with wa1/wa2 over this lane's 32 k's, reduce over q.
    float p1 = 0.f, p2 = 0.f;
    {
        const float* w1p = wa + q * 8;
        const float* w2p = wa + F + q * 8;
        #pragma unroll
        for (int kt = 0; kt < 4; ++kt) {
            const float4 u0 = *reinterpret_cast<const float4*>(w1p + kt * 32);
            const float4 u1 = *reinterpret_cast<const float4*>(w1p + kt * 32 + 4);
            const float4 v0 = *reinterpret_cast<const float4*>(w2p + kt * 32);
            const float4 v1 = *reinterpret_cast<const float4*>(w2p + kt * 32 + 4);
            const float4 xa = xf[2*kt], xb = xf[2*kt+1];
            p1 = fmaf(xa.x,u0.x,p1); p1 = fmaf(xa.y,u0.y,p1);
            p1 = fmaf(xa.z,u0.z,p1); p1 = fmaf(xa.w,u0.w,p1);
            p1 = fmaf(xb.x,u1.x,p1); p1 = fmaf(xb.y,u1.y,p1);
            p1 = fmaf(xb.z,u1.z,p1); p1 = fmaf(xb.w,u1.w,p1);
            p2 = fmaf(xa.x,v0.x,p2); p2 = fmaf(xa.y,v0.y,p2);
            p2 = fmaf(xa.z,v0.z,p2); p2 = fmaf(xa.w,v0.w,p2);
            p2 = fmaf(xb.x,v1.x,p2); p2 = fmaf(xb.y,v1.y,p2);
            p2 = fmaf(xb.z,v1.z,p2); p2 = fmaf(xb.w,v1.w,p2);
        }
    }
    p1 += __shfl_xor(p1, 16); p1 += __shfl_xor(p1, 32);
    p2 += __shfl_xor(p2, 16); p2 += __shfl_xor(p2, 32);
    if (lane < 16) {
        s1[r0 + m] = p1;
        s2[r0 + m] = p2;
    }

    // x16 store: same casts as the old GEMM B-fragment build.
    #pragma unroll
    for (int kt = 0; kt < 4; ++kt) {
        const float4 qa = xf[2*kt], qb = xf[2*kt+1];
        union { bf16x8 v; uint4 u; } f;
        f.v[0] = (__bf16)qa.x; f.v[1] = (__bf16)qa.y; f.v[2] = (__bf16)qa.z; f.v[3] = (__bf16)qa.w;
        f.v[4] = (__bf16)qb.x; f.v[5] = (__bf16)qb.y; f.v[6] = (__bf16)qb.z; f.v[7] = (__bf16)qb.w;
        *reinterpret_cast<uint4*>(x16 + (r0 + m) * F + kt * 32 + q * 8) = f.u;
    }
}

// Main: gather + softmax + z-accumulate (verbatim old attn structure, on
// x16), z -> wave-private LDS (bf16, XOR-swizzled), then the old MFMA tile
// computes z@W^T and stores elu(out). 64 nodes per block, grid 1250.
// LDS 32+16 = 48 KB -> 3 blocks/CU (144 KB), 12 waves/CU.
__global__ __launch_bounds__(256, 3) void gat_main(
    const int* __restrict__ adj,
    const __hip_bfloat16* __restrict__ x16,
    const __hip_bfloat16* __restrict__ wt,
    const float* __restrict__ s1,
    const float* __restrict__ s2,
    float* __restrict__ out)
{
    __shared__ __hip_bfloat16 wl[F][F];       // 32 KB
    __shared__ __hip_bfloat16 zl[4][16][F];   // 16 KB, wave-private [wid]

    const int bid  = blockIdx.x;
    const int t    = threadIdx.x;
    const int lane = t & 63;
    const int wid  = t >> 6;

    // Stage wt -> LDS (XOR-swizzled 16B chunks: phys chunk = c8 ^ (row&7)).
    {
        const uint4* wg = reinterpret_cast<const uint4*>(wt);
        #pragma unroll
        for (int i = 0; i < 8; ++i) {
            const int g   = t + 256 * i;
            const int row = g >> 4;
            const int c8  = g & 15;
            *reinterpret_cast<uint4*>(&wl[row][((c8 ^ (row & 7)) * 8)]) = wg[g];
        }
    }
    __syncthreads();

    const int d   = lane & 15;
    const int g16 = lane & 48;
    const int g   = lane >> 4;

    // ---- Gather phase: 4 passes x 4 nodes; lane (g,d) owns feats
    // [d*8, d*8+8) of node n0+g; z written to wave-private LDS.
    #pragma unroll
    for (int p = 0; p < 4; ++p) {
        const int n0    = bid * 64 + wid * 16 + p * 4;   // pass's first node
        const int batch = n0 / LSEQ;                     // passes never straddle
        const int base  = batch * LSEQ;

        // adj for 4 nodes: 64 contiguous ints, fully coalesced.
        const int av = adj[(size_t)n0 * DEG + lane];

        const float sv = s1[base + av];
        float s2l = (d == 0) ? s2[base + av] : 0.f;
        const float s2v = __shfl(s2l, g16);
        const float e = sv + s2v;
        const float tv = e > 0.f ? e : ALPHA * e;

        // softmax within each 16-lane group.
        float mx = tv;
        #pragma unroll
        for (int off = 1; off < 16; off <<= 1) mx = fmaxf(mx, __shfl_xor(mx, off));
        const float w = __expf(tv - mx);
        float pp = w;
        #pragma unroll
        for (int off = 1; off < 16; off <<= 1) pp += __shfl_xor(pp, off);
        const float attn = w / pp;

        // Gather x16 rows: 16B per lane per neighbor row.
        const char* yb = reinterpret_cast<const char*>(x16 + ((size_t)base << 7)) + d * 16;
        float acc[8] = {0.f, 0.f, 0.f, 0.f, 0.f, 0.f, 0.f, 0.f};

        uint4 va[8], vb[8];
        #pragma unroll
        for (int k = 0; k < 8; ++k) {
            const int r = __shfl(av, g16 + k);
            va[k] = *reinterpret_cast<const uint4*>(yb + ((size_t)r << 8));
        }
        #pragma unroll
        for (int k = 0; k < 8; ++k) {
            const int r = __shfl(av, g16 + 8 + k);
            vb[k] = *reinterpret_cast<const uint4*>(yb + ((size_t)r << 8));
        }

        #pragma unroll
        for (int k = 0; k < 8; ++k) {
            const float wk = __shfl(attn, g16 + k);
            const uint4 vv = va[k];
            acc[0] = fmaf(wk, bf_lo(vv.x), acc[0]);
            acc[1] = fmaf(wk, bf_hi(vv.x), acc[1]);
            acc[2] = fmaf(wk, bf_lo(vv.y), acc[2]);
            acc[3] = fmaf(wk, bf_hi(vv.y), acc[3]);
            acc[4] = fmaf(wk, bf_lo(vv.z), acc[4]);
            acc[5] = fmaf(wk, bf_hi(vv.z), acc[5]);
            acc[6] = fmaf(wk, bf_lo(vv.w), acc[6]);
            acc[7] = fmaf(wk, bf_hi(vv.w), acc[7]);
        }
        #pragma unroll
        for (int k = 0; k < 8; ++k) {
            const float wk = __shfl(attn, g16 + 8 + k);
            const uint4 vv = vb[k];
            acc[0] = fmaf(wk, bf_lo(vv.x), acc[0]);
            acc[1] = fmaf(wk, bf_hi(vv.x), acc[1]);
            acc[2] = fmaf(wk, bf_lo(vv.y), acc[2]);
            acc[3] = fmaf(wk, bf_hi(vv.y), acc[3]);
            acc[4] = fmaf(wk, bf_lo(vv.z), acc[4]);
            acc[5] = fmaf(wk, bf_hi(vv.z), acc[5]);
            acc[6] = fmaf(wk, bf_lo(vv.w), acc[6]);
            acc[7] = fmaf(wk, bf_hi(vv.w), acc[7]);
        }

        // z -> LDS: row r = p*4+g, logical chunk d, phys chunk d^(r&7).
        union { uint4 u; __hip_bfloat162 h[4]; } pz;
        pz.h[0] = __float22bfloat162_rn(make_float2(acc[0], acc[1]));
        pz.h[1] = __float22bfloat162_rn(make_float2(acc[2], acc[3]));
        pz.h[2] = __float22bfloat162_rn(make_float2(acc[4], acc[5]));
        pz.h[3] = __float22bfloat162_rn(make_float2(acc[6], acc[7]));
        const int r = p * 4 + g;
        *reinterpret_cast<uint4*>(&zl[wid][r][((d ^ (r & 7)) * 8)]) = pz.u;
    }

    __syncthreads();   // zl complete (wave-private, but barrier is cheap+safe)

    // ---- MFMA phase: out rows = this wave's 16 nodes. A = wt (LDS),
    // B = z (LDS). Same tile as the old gemm; store elu(fp32) directly.
    {
        const int m = lane & 15;
        const int q = lane >> 4;
        const size_t row0 = (size_t)bid * 64 + wid * 16;

        // B-fragments: z[row m][k = kt*32+q*8+j], chunk (4kt+q)^(m&7).
        union { uint4 u; bf16x8 v; } bfr[4];
        #pragma unroll
        for (int kt = 0; kt < 4; ++kt)
            bfr[kt].u = *reinterpret_cast<const uint4*>(
                            &zl[wid][m][(((kt * 4 + q) ^ (m & 7)) * 8)]);

        #pragma unroll
        for (int ct = 0; ct < 8; ++ct) {
            union { uint4 u; bf16x8 v; } afr[4];
            const int row = ct * 16 + m;
            #pragma unroll
            for (int kt = 0; kt < 4; ++kt)
                afr[kt].u = *reinterpret_cast<const uint4*>(
                                &wl[row][(((kt * 4 + q) ^ (m & 7)) * 8)]);

            f32x4 acc = {0.f, 0.f, 0.f, 0.f};
            #pragma unroll
            for (int kt = 0; kt < 4; ++kt)
                acc = __builtin_amdgcn_mfma_f32_16x16x32_bf16(afr[kt].v, bfr[kt].v, acc, 0, 0, 0);

            const float4 o = make_float4(elu_f(acc[0]), elu_f(acc[1]),
                                         elu_f(acc[2]), elu_f(acc[3]));
            *reinterpret_cast<float4*>(out + (row0 + m) * F + ct * 16 + q * 4) = o;
        }
    }
}

extern "C" void kernel_launch(void* const* d_in, const int* in_sizes, int n_in,
                              void* d_out, int out_size, void* d_ws, size_t ws_size,
                              hipStream_t stream) {
    const float* x   = (const float*)d_in[0];
    const int*   adj = (const int*)d_in[1];
    const float* W   = (const float*)d_in[2];
    const float* a   = (const float*)d_in[3];
    float* out = (float*)d_out;

    const int BL = in_sizes[0] / F;   // bs*L = 80000

    __hip_bfloat16* x16 = (__hip_bfloat16*)d_ws;
    float* s1 = (float*)((char*)d_ws + (size_t)BL * F * sizeof(__hip_bfloat16));
    float* s2 = s1 + BL;
    __hip_bfloat16* wt = (__hip_bfloat16*)(s2 + BL);
    float* wa = (float*)(wt + F * F);

    gat_prep<<<16,      256, 0, stream>>>(W, a, wt, wa);
    gat_rows<<<BL / 64, 256, 0, stream>>>(x, wa, x16, s1, s2);
    gat_main<<<BL / 64, 256, 0, stream>>>(adj, x16, wt, s1, s2, out);
}